// Round 11
// baseline (324.237 us; speedup 1.0000x reference)
//
#include <hip/hip_runtime.h>

// Self-attention block (non-local): B=8, C=256, H=W=64 -> N=4096, dk=64.
// out = x + gamma * softmax((Wq x)^T (Wk x) / 8) applied to (Wv x).
// Pipeline: prep (weights->bf16, fold log2e/8 into Wq) -> proj (MFMA GEMM,
// in-LDS transpose of x) -> flash.
// R11 flash = R9 body reshaped to m-block 32: grid 1024 (4 blocks/CU
// schedulable vs 512's 2), launch_bounds(256,3).  kv-block 64, wave kv-slice
// 16, S via 16x16x32 MFMA; V straight L2->regs (loaded top of region A,
// consumed after the barrier -- cannot sink, small enough to never spill);
// P through 2x4KB double-buffered XOR-swizzled LDS, ONE barrier/iter.
// Max-free softmax (logits O(1) by construction), direct f32x4 epilogue.

typedef __attribute__((ext_vector_type(8)))  short short8;
typedef __attribute__((ext_vector_type(4)))  short short4v;
typedef __attribute__((ext_vector_type(16))) float f32x16;
typedef __attribute__((ext_vector_type(4)))  float f32x4;

#define B_   8
#define C_   256
#define N_   4096
#define DK_  64
// log2(e) / sqrt(dk) = 1.4426950408889634 / 8
#define QSCL 0.18033688011112043f

#if defined(__has_builtin)
#if __has_builtin(__builtin_amdgcn_exp2f)
#define EXP2F(x) __builtin_amdgcn_exp2f(x)
#else
#define EXP2F(x) exp2f(x)
#endif
#else
#define EXP2F(x) exp2f(x)
#endif

// float -> bf16 bits, round-to-nearest-even (inputs are finite; no NaN path)
__device__ __forceinline__ unsigned short bfb(float f) {
  unsigned u = __builtin_bit_cast(unsigned, f);
  unsigned r = (u + 0x7fffu + ((u >> 16) & 1u)) >> 16;
  return (unsigned short)r;
}

// packed f32x2 -> bf16x2 (low = a, high = b), RNE
__device__ __forceinline__ unsigned cvtpk(float a, float b) {
  unsigned r;
  asm("v_cvt_pk_bf16_f32 %0, %1, %2" : "=v"(r) : "v"(a), "v"(b));
  return r;
}

// ---------------------------------------------------------------------------
// Kernel 1: weight prep.  W'[384][256] bf16 = [Wq*QSCL ; Wk ; Wv], bias'[384].
// ---------------------------------------------------------------------------
__global__ void prep_kernel(const float* __restrict__ Wq, const float* __restrict__ bq,
                            const float* __restrict__ Wk, const float* __restrict__ bk,
                            const float* __restrict__ Wv, const float* __restrict__ bv,
                            unsigned short* __restrict__ Wc, float* __restrict__ biasc) {
  int idx = blockIdx.x * 256 + threadIdx.x;
  if (idx < 384 * 256) {
    int ch = idx >> 8, c = idx & 255;
    float v;
    if (ch < 64)       v = Wq[ch * 256 + c] * QSCL;
    else if (ch < 128) v = Wk[(ch - 64) * 256 + c];
    else               v = Wv[(ch - 128) * 256 + c];
    Wc[idx] = bfb(v);
  }
  if (idx < 384) {
    float bb;
    if (idx < 64)       bb = bq[idx] * QSCL;
    else if (idx < 128) bb = bk[idx - 64];
    else                bb = bv[idx - 128];
    biasc[idx] = bb;
  }
}

// ---------------------------------------------------------------------------
// Kernel 2: projections.  Per (batch, 64-row n-block): stage x[256c][64n]
// transposed into LDS as bf16 (XOR-swizzled), then OUT[n][ch] = Xt * W'^T via
// 32x32x16 bf16 MFMA.  Outputs: Qt,Kt [B][N][64] (n-major), V [B][C][N].
// ---------------------------------------------------------------------------
__global__ __launch_bounds__(256, 2) void proj_kernel(
    const float* __restrict__ x, const unsigned short* __restrict__ Wc,
    const float* __restrict__ biasc, unsigned short* __restrict__ Qt,
    unsigned short* __restrict__ Kt, unsigned short* __restrict__ V) {
  __shared__ unsigned short XT[64 * 256];  // [n][c] bf16, swizzled, 32 KiB
  const int tid = threadIdx.x;
  const int b = blockIdx.y;
  const int n0 = blockIdx.x * 64;

  // stage: x[b][c][n0+0..63] fp32 -> XT[n][c] bf16 (transpose), swizzle:
  // ushort idx = n*256 + (((c>>3) ^ (n&15))<<3) + (c&7)
  {
    const f32x4* x4 = (const f32x4*)(x + ((size_t)b * C_) * N_ + n0);
    int c = tid >> 4;                  // 0..15 (+16 per pass)
    const int nl = (tid & 15) << 2;    // 0,4,...,60
#pragma unroll
    for (int p = 0; p < 16; ++p, c += 16) {
      f32x4 v = x4[(size_t)c * (N_ / 4) + (nl >> 2)];
#pragma unroll
      for (int i = 0; i < 4; ++i) {
        int n = nl + i;
        XT[n * 256 + ((((c >> 3) ^ (n & 15)) << 3) | (c & 7))] = bfb(v[i]);
      }
    }
  }
  __syncthreads();

  const int lane = tid & 63, li = lane & 31, hi = lane >> 5;
  const int w = tid >> 6;
  const int ch0 = 96 * w;  // this wave's 96 output channels (3 x 32)

  f32x16 acc[2][3];
#pragma unroll
  for (int mt = 0; mt < 2; ++mt)
#pragma unroll
    for (int j = 0; j < 3; ++j)
#pragma unroll
      for (int r = 0; r < 16; ++r) acc[mt][j][r] = 0.f;

  const short8* Wc8 = (const short8*)Wc;
#pragma unroll
  for (int ks = 0; ks < 16; ++ks) {
    // A-frags: lane holds Xt[n=32*mt+li][c=16*ks+8*hi .. +8]
    int chunk = 2 * ks + hi;
    short8 a0 = *(const short8*)&XT[(li) * 256 + ((chunk ^ (li & 15)) << 3)];
    short8 a1 = *(const short8*)&XT[(32 + li) * 256 + ((chunk ^ (li & 15)) << 3)];
#pragma unroll
    for (int j = 0; j < 3; ++j) {
      short8 bf = Wc8[(size_t)(ch0 + 32 * j + li) * 32 + chunk];
      acc[0][j] = __builtin_amdgcn_mfma_f32_32x32x16_bf16(a0, bf, acc[0][j], 0, 0, 0);
      acc[1][j] = __builtin_amdgcn_mfma_f32_32x32x16_bf16(a1, bf, acc[1][j], 0, 0, 0);
    }
  }

  // epilogue: D[row=n][col=ch], row = (r&3)+8*(r>>2)+4*hi + 32*mt, col = li
#pragma unroll
  for (int j = 0; j < 3; ++j) {
    const int chb = ch0 + 32 * j;  // wave-uniform 32-block, never straddles Q/K/V
    const int ch = chb + li;
    const float bias = biasc[ch];
#pragma unroll
    for (int mt = 0; mt < 2; ++mt) {
      if (chb < 64) {
#pragma unroll
        for (int r = 0; r < 16; ++r) {
          int n = n0 + 32 * mt + (r & 3) + 8 * (r >> 2) + 4 * hi;
          Qt[((size_t)(b * N_ + n) << 6) + ch] = bfb(acc[mt][j][r] + bias);
        }
      } else if (chb < 128) {
#pragma unroll
        for (int r = 0; r < 16; ++r) {
          int n = n0 + 32 * mt + (r & 3) + 8 * (r >> 2) + 4 * hi;
          Kt[((size_t)(b * N_ + n) << 6) + (ch - 64)] = bfb(acc[mt][j][r] + bias);
        }
      } else {
        const int cv = ch - 128;
#pragma unroll
        for (int q = 0; q < 4; ++q) {  // 4 consecutive n per 8B store
          short4v pk;
#pragma unroll
          for (int i = 0; i < 4; ++i) pk[i] = (short)bfb(acc[mt][j][4 * q + i] + bias);
          int n = n0 + 32 * mt + 8 * q + 4 * hi;
          *(short4v*)&V[(size_t)(b * C_ + cv) * N_ + n] = pk;
        }
      }
    }
  }
}

// ---------------------------------------------------------------------------
// Kernel 3: attention.  Grid 1024 x 256 threads (4 waves).
// b = id & 7 (batch <-> XCD), m0 = (id >> 3) * 32.  kv-block 64, 64 iters.
// Region A(t): load this iter's V frags (8 x 16B, consumed after the
// barrier) + K frags (2 x 16B); S for the wave's 16-kv slice x 32 m via
// 16x16x32 MFMA; exp2 + cvtpk -> one 8B P store per mt.  __syncthreads.
// Region B(t): PV 16x16x32, P A-frags from swizzled LDS, V from regs.
// P byte addr: buf*4096 + m*128 + (kvbyte ^ ((m&7)<<4)); one barrier/iter
// (P double-buffered: BAR(t+1) orders B(t) reads before A(t+2) writes).
// ---------------------------------------------------------------------------
__global__ __launch_bounds__(256, 3) void flash_kernel(
    const unsigned short* __restrict__ Qt, const unsigned short* __restrict__ Kt,
    const unsigned short* __restrict__ V, const float* __restrict__ x,
    const float* __restrict__ gamma, float* __restrict__ out) {
  __shared__ unsigned short P[2][32 * 64];  // 2 x 4 KiB, swizzled
  __shared__ float den_lds[4][2][16];       // [wave][mt][lc]

  const int tid = threadIdx.x;
  const int lane = tid & 63;
  const int lc = lane & 15, lg = lane >> 4;
  const int w = tid >> 6;
  const int id = blockIdx.x;
  const int b = id & 7;                // batch == XCD (round-robin dispatch)
  const int m0 = (id >> 3) << 5;       // 32-row m-block

  // Q B-frags: qb[mt][ks] = Q[m0+16mt+lc][dk = 32ks+8lg .. +7]
  short8 qb[2][2];
#pragma unroll
  for (int mt = 0; mt < 2; ++mt)
#pragma unroll
    for (int ks = 0; ks < 2; ++ks)
      qb[mt][ks] = *(const short8*)(Qt + ((size_t)b * N_ + m0 + 16 * mt + lc) * 64 +
                                    32 * ks + 8 * lg);

  f32x4 acc16[2][4];  // [t16 m-subtile][ct c-subtile]
#pragma unroll
  for (int t16 = 0; t16 < 2; ++t16)
#pragma unroll
    for (int ct = 0; ct < 4; ++ct)
#pragma unroll
      for (int r = 0; r < 4; ++r) acc16[t16][ct][r] = 0.f;
  float den[2] = {0.f, 0.f};

  // K base: row kv = kv0 + 16w + lc, dk bytes 16lg + {0,64}; +8192B per iter
  const char* Kp = (const char*)Kt + ((size_t)b * N_ + 16 * w + lc) * 128 + 16 * lg;
  // V row pointers: c = 64w + 16ct + lc, kv elem 8lg; +128B per iter
  const unsigned short* vp[4];
#pragma unroll
  for (int ct = 0; ct < 4; ++ct)
    vp[ct] = V + ((size_t)b * C_ + 64 * w + 16 * ct + lc) * N_ + 8 * lg;

  const int pkey = (lc & 7) << 4;      // P swizzle key (m&7 == lc&7)
  const int pwcol = (32 * w + 8 * lg) ^ pkey;  // P-write column byte

#pragma unroll 2
  for (int t = 0; t < 64; ++t) {
    const int kv0 = t << 6;
    char* Pb = (char*)P[t & 1];

    // ---- region A: V frags for B(t) (ride regs across the barrier) ----
    short8 vf[2][4];
#pragma unroll
    for (int ks = 0; ks < 2; ++ks)
#pragma unroll
      for (int ct = 0; ct < 4; ++ct)
        vf[ks][ct] = *(const short8*)(vp[ct] + kv0 + 32 * ks);
    // K frags for this iter's S
    short8 kf0 = *(const short8*)(Kp + (size_t)t * 8192);
    short8 kf1 = *(const short8*)(Kp + (size_t)t * 8192 + 64);
    asm volatile("" ::: "memory");  // pin loads above the compute

    // ---- S: 16kv x 32m, 2 m-tiles x (K=32 x 2) ----
#pragma unroll
    for (int mt = 0; mt < 2; ++mt) {
      f32x4 st = {0.f, 0.f, 0.f, 0.f};
      st = __builtin_amdgcn_mfma_f32_16x16x32_bf16(kf0, qb[mt][0], st, 0, 0, 0);
      st = __builtin_amdgcn_mfma_f32_16x16x32_bf16(kf1, qb[mt][1], st, 0, 0, 0);
      // lane holds S[kv = kv0+16w+4lg+r][m = m0+16mt+lc], r=0..3
      float e0 = EXP2F(st[0]), e1 = EXP2F(st[1]);
      float e2 = EXP2F(st[2]), e3 = EXP2F(st[3]);
      den[mt] += (e0 + e1) + (e2 + e3);
      unsigned lo = cvtpk(e0, e1), hh = cvtpk(e2, e3);
      unsigned long long vv = (unsigned long long)lo | ((unsigned long long)hh << 32);
      *(unsigned long long*)(Pb + (16 * mt + lc) * 128 + pwcol) = vv;
    }

    __syncthreads();  // P[t&1] ready; V/K regs ride across

    // ---- region B: PV (16x16x32), 2 k-steps of 32 kv ----
#pragma unroll
    for (int ks = 0; ks < 2; ++ks) {
      short8 pf[2];
#pragma unroll
      for (int t16 = 0; t16 < 2; ++t16)
        pf[t16] = *(const short8*)(Pb + (16 * t16 + lc) * 128 +
                                   ((64 * ks + 16 * lg) ^ pkey));
      __builtin_amdgcn_s_setprio(1);
#pragma unroll
      for (int ct = 0; ct < 4; ++ct)
#pragma unroll
        for (int t16 = 0; t16 < 2; ++t16)
          acc16[t16][ct] = __builtin_amdgcn_mfma_f32_16x16x32_bf16(
              pf[t16], vf[ks][ct], acc16[t16][ct], 0, 0, 0);
      __builtin_amdgcn_s_setprio(0);
    }
    // no second barrier: P dbuf; BAR(t+1) orders B(t) before A(t+2)
  }

  // ---- den reduction: lg-groups (shfl) then cross-wave (LDS) ----
#pragma unroll
  for (int mt = 0; mt < 2; ++mt) {
    float d = den[mt];
    d += __shfl_xor(d, 16);
    d += __shfl_xor(d, 32);
    if (lg == 0) den_lds[w][mt][lc] = d;
  }
  __syncthreads();

  const float g = gamma[0];
  float ig[2];
#pragma unroll
  for (int mt = 0; mt < 2; ++mt) {
    float dtot = den_lds[0][mt][lc] + den_lds[1][mt][lc] +
                 den_lds[2][mt][lc] + den_lds[3][mt][lc];
    ig[mt] = g / dtot;  // lane's lc: gamma/den for m-row m0+16mt+lc
  }

  // ---- epilogue: lane holds O[m=16t16+4lg+r][c=16ct+lc]; f32x4 over m ----
#pragma unroll
  for (int t16 = 0; t16 < 2; ++t16) {
    f32x4 idn;
#pragma unroll
    for (int r = 0; r < 4; ++r)
      idn[r] = __shfl(ig[t16], 4 * lg + r);
#pragma unroll
    for (int ct = 0; ct < 4; ++ct) {
      size_t off = ((size_t)b * C_ + 64 * w + 16 * ct + lc) * N_ + m0 + 16 * t16 + 4 * lg;
      f32x4 xv = *(const f32x4*)(x + off);
      f32x4 o;
#pragma unroll
      for (int r = 0; r < 4; ++r) o[r] = xv[r] + idn[r] * acc16[t16][ct][r];
      *(f32x4*)(out + off) = o;
    }
  }
}

// ---------------------------------------------------------------------------
extern "C" void kernel_launch(void* const* d_in, const int* in_sizes, int n_in,
                              void* d_out, int out_size, void* d_ws, size_t ws_size,
                              hipStream_t stream) {
  const float* x = (const float*)d_in[0];
  const float* Wq = (const float*)d_in[1];
  const float* bq = (const float*)d_in[2];
  const float* Wk = (const float*)d_in[3];
  const float* bk = (const float*)d_in[4];
  const float* Wv = (const float*)d_in[5];
  const float* bv = (const float*)d_in[6];
  const float* gamma = (const float*)d_in[7];
  float* out = (float*)d_out;

  char* ws = (char*)d_ws;
  unsigned short* Wc = (unsigned short*)(ws);                    // 196608 B
  float* biasc = (float*)(ws + 196608);                          // 1536 B
  unsigned short* Qt = (unsigned short*)(ws + 198144);           // 4 MiB
  unsigned short* Kt = (unsigned short*)(ws + 198144 + 4194304); // 4 MiB
  unsigned short* Vv = (unsigned short*)(ws + 198144 + 8388608); // 16 MiB
  // total ws use: ~25.4 MB

  prep_kernel<<<384, 256, 0, stream>>>(Wq, bq, Wk, bk, Wv, bv, Wc, biasc);
  proj_kernel<<<dim3(64, 8), 256, 0, stream>>>(x, Wc, biasc, Qt, Kt, Vv);
  flash_kernel<<<1024, 256, 0, stream>>>(Qt, Kt, Vv, x, gamma, out);
}

// Round 12
// 197.342 us; speedup vs baseline: 1.6430x; 1.6430x over previous
//
#include <hip/hip_runtime.h>

// Self-attention block (non-local): B=8, C=256, H=W=64 -> N=4096, dk=64.
// out = x + gamma * softmax((Wq x)^T (Wk x) / 8) applied to (Wv x).
// Pipeline: prep (weights->bf16, fold log2e/8 into Wq) -> proj (MFMA GEMM,
// in-LDS transpose of x) -> flash.
// R12 flash = R9 geometry (m-block 64, kv-block 64, grid 512) + prefetch
// placed on the CORRECT side of the barrier: iteration t+1's V/K loads are
// issued at the TOP of region B(t) (just after __syncthreads), so their L2
// latency hides under PV(t)'s MFMAs, S(t+1) starts with ~zero wait, and the
// next barrier's mandatory vmcnt(0) drain finds them already complete.
// (R10 issued them in region A -- before the barrier -- so every barrier
// drained fresh loads and the L2 latency landed on the block critical path.)
// Ping-pong register buffers (static names, rule 20), ONE barrier/iter.

typedef __attribute__((ext_vector_type(8)))  short short8;
typedef __attribute__((ext_vector_type(4)))  short short4v;
typedef __attribute__((ext_vector_type(16))) float f32x16;
typedef __attribute__((ext_vector_type(4)))  float f32x4;

#define B_   8
#define C_   256
#define N_   4096
#define DK_  64
// log2(e) / sqrt(dk) = 1.4426950408889634 / 8
#define QSCL 0.18033688011112043f

#if defined(__has_builtin)
#if __has_builtin(__builtin_amdgcn_exp2f)
#define EXP2F(x) __builtin_amdgcn_exp2f(x)
#else
#define EXP2F(x) exp2f(x)
#endif
#else
#define EXP2F(x) exp2f(x)
#endif

// float -> bf16 bits, round-to-nearest-even (inputs are finite; no NaN path)
__device__ __forceinline__ unsigned short bfb(float f) {
  unsigned u = __builtin_bit_cast(unsigned, f);
  unsigned r = (u + 0x7fffu + ((u >> 16) & 1u)) >> 16;
  return (unsigned short)r;
}

// packed f32x2 -> bf16x2 (low = a, high = b), RNE
__device__ __forceinline__ unsigned cvtpk(float a, float b) {
  unsigned r;
  asm("v_cvt_pk_bf16_f32 %0, %1, %2" : "=v"(r) : "v"(a), "v"(b));
  return r;
}

// ---------------------------------------------------------------------------
// Kernel 1: weight prep.  W'[384][256] bf16 = [Wq*QSCL ; Wk ; Wv], bias'[384].
// ---------------------------------------------------------------------------
__global__ void prep_kernel(const float* __restrict__ Wq, const float* __restrict__ bq,
                            const float* __restrict__ Wk, const float* __restrict__ bk,
                            const float* __restrict__ Wv, const float* __restrict__ bv,
                            unsigned short* __restrict__ Wc, float* __restrict__ biasc) {
  int idx = blockIdx.x * 256 + threadIdx.x;
  if (idx < 384 * 256) {
    int ch = idx >> 8, c = idx & 255;
    float v;
    if (ch < 64)       v = Wq[ch * 256 + c] * QSCL;
    else if (ch < 128) v = Wk[(ch - 64) * 256 + c];
    else               v = Wv[(ch - 128) * 256 + c];
    Wc[idx] = bfb(v);
  }
  if (idx < 384) {
    float bb;
    if (idx < 64)       bb = bq[idx] * QSCL;
    else if (idx < 128) bb = bk[idx - 64];
    else                bb = bv[idx - 128];
    biasc[idx] = bb;
  }
}

// ---------------------------------------------------------------------------
// Kernel 2: projections.  Per (batch, 64-row n-block): stage x[256c][64n]
// transposed into LDS as bf16 (XOR-swizzled), then OUT[n][ch] = Xt * W'^T via
// 32x32x16 bf16 MFMA.  Outputs: Qt,Kt [B][N][64] (n-major), V [B][C][N].
// ---------------------------------------------------------------------------
__global__ __launch_bounds__(256, 2) void proj_kernel(
    const float* __restrict__ x, const unsigned short* __restrict__ Wc,
    const float* __restrict__ biasc, unsigned short* __restrict__ Qt,
    unsigned short* __restrict__ Kt, unsigned short* __restrict__ V) {
  __shared__ unsigned short XT[64 * 256];  // [n][c] bf16, swizzled, 32 KiB
  const int tid = threadIdx.x;
  const int b = blockIdx.y;
  const int n0 = blockIdx.x * 64;

  // stage: x[b][c][n0+0..63] fp32 -> XT[n][c] bf16 (transpose), swizzle:
  // ushort idx = n*256 + (((c>>3) ^ (n&15))<<3) + (c&7)
  {
    const f32x4* x4 = (const f32x4*)(x + ((size_t)b * C_) * N_ + n0);
    int c = tid >> 4;                  // 0..15 (+16 per pass)
    const int nl = (tid & 15) << 2;    // 0,4,...,60
#pragma unroll
    for (int p = 0; p < 16; ++p, c += 16) {
      f32x4 v = x4[(size_t)c * (N_ / 4) + (nl >> 2)];
#pragma unroll
      for (int i = 0; i < 4; ++i) {
        int n = nl + i;
        XT[n * 256 + ((((c >> 3) ^ (n & 15)) << 3) | (c & 7))] = bfb(v[i]);
      }
    }
  }
  __syncthreads();

  const int lane = tid & 63, li = lane & 31, hi = lane >> 5;
  const int w = tid >> 6;
  const int ch0 = 96 * w;  // this wave's 96 output channels (3 x 32)

  f32x16 acc[2][3];
#pragma unroll
  for (int mt = 0; mt < 2; ++mt)
#pragma unroll
    for (int j = 0; j < 3; ++j)
#pragma unroll
      for (int r = 0; r < 16; ++r) acc[mt][j][r] = 0.f;

  const short8* Wc8 = (const short8*)Wc;
#pragma unroll
  for (int ks = 0; ks < 16; ++ks) {
    // A-frags: lane holds Xt[n=32*mt+li][c=16*ks+8*hi .. +8]
    int chunk = 2 * ks + hi;
    short8 a0 = *(const short8*)&XT[(li) * 256 + ((chunk ^ (li & 15)) << 3)];
    short8 a1 = *(const short8*)&XT[(32 + li) * 256 + ((chunk ^ (li & 15)) << 3)];
#pragma unroll
    for (int j = 0; j < 3; ++j) {
      short8 bf = Wc8[(size_t)(ch0 + 32 * j + li) * 32 + chunk];
      acc[0][j] = __builtin_amdgcn_mfma_f32_32x32x16_bf16(a0, bf, acc[0][j], 0, 0, 0);
      acc[1][j] = __builtin_amdgcn_mfma_f32_32x32x16_bf16(a1, bf, acc[1][j], 0, 0, 0);
    }
  }

  // epilogue: D[row=n][col=ch], row = (r&3)+8*(r>>2)+4*hi + 32*mt, col = li
#pragma unroll
  for (int j = 0; j < 3; ++j) {
    const int chb = ch0 + 32 * j;  // wave-uniform 32-block, never straddles Q/K/V
    const int ch = chb + li;
    const float bias = biasc[ch];
#pragma unroll
    for (int mt = 0; mt < 2; ++mt) {
      if (chb < 64) {
#pragma unroll
        for (int r = 0; r < 16; ++r) {
          int n = n0 + 32 * mt + (r & 3) + 8 * (r >> 2) + 4 * hi;
          Qt[((size_t)(b * N_ + n) << 6) + ch] = bfb(acc[mt][j][r] + bias);
        }
      } else if (chb < 128) {
#pragma unroll
        for (int r = 0; r < 16; ++r) {
          int n = n0 + 32 * mt + (r & 3) + 8 * (r >> 2) + 4 * hi;
          Kt[((size_t)(b * N_ + n) << 6) + (ch - 64)] = bfb(acc[mt][j][r] + bias);
        }
      } else {
        const int cv = ch - 128;
#pragma unroll
        for (int q = 0; q < 4; ++q) {  // 4 consecutive n per 8B store
          short4v pk;
#pragma unroll
          for (int i = 0; i < 4; ++i) pk[i] = (short)bfb(acc[mt][j][4 * q + i] + bias);
          int n = n0 + 32 * mt + 8 * q + 4 * hi;
          *(short4v*)&V[(size_t)(b * C_ + cv) * N_ + n] = pk;
        }
      }
    }
  }
}

// ---------------------------------------------------------------------------
// Kernel 3: attention.  Grid 512 x 256 threads (4 waves).
// b = id & 7 (batch <-> XCD), m0 = (id >> 3) * 64.  kv-block 64, 64 iters,
// loop unrolled x2 with ping-pong register buffers (vfA/vfB, kfA*/kfB*).
// Iter body: A: S for the wave's 16-kv slice x 64 m via 16x16x32 MFMA using
// CUR K regs (loaded last iter -> ~zero wait); exp2+cvtpk -> P (swizzled
// LDS, dbuf).  __syncthreads (vmcnt drain finds nothing fresh).  B: FIRST
// issue V/K for t+1 into NXT regs (L2 latency hides under PV), then PV
// 16x16x32 from P + CUR V regs; tail asm fence keeps the loads in B.
// P byte addr: buf*8192 + m*128 + (kvbyte ^ ((m&7)<<4)).
// ---------------------------------------------------------------------------
#define ITER_BODY(VFC, KC0, KC1, VFN, KN0, KN1, PB, TN)                        \
  {                                                                            \
    char* Pb_ = (char*)P[PB];                                                  \
    _Pragma("unroll") for (int mt = 0; mt < 4; ++mt) {                         \
      f32x4 st = {0.f, 0.f, 0.f, 0.f};                                         \
      st = __builtin_amdgcn_mfma_f32_16x16x32_bf16(KC0, qb[mt][0], st, 0, 0, 0);\
      st = __builtin_amdgcn_mfma_f32_16x16x32_bf16(KC1, qb[mt][1], st, 0, 0, 0);\
      float e0 = EXP2F(st[0]), e1 = EXP2F(st[1]);                              \
      float e2 = EXP2F(st[2]), e3 = EXP2F(st[3]);                              \
      den[mt] += (e0 + e1) + (e2 + e3);                                        \
      unsigned lo_ = cvtpk(e0, e1);                                            \
      unsigned hh_ = cvtpk(e2, e3);                                            \
      unsigned long long vv_ =                                                 \
          (unsigned long long)lo_ | ((unsigned long long)hh_ << 32);           \
      *(unsigned long long*)(Pb_ + (16 * mt + lc) * 128 + pwcol) = vv_;        \
    }                                                                          \
    __syncthreads();                                                           \
    /* prefetch t+1 operands: latency hides under the PV MFMAs below */        \
    {                                                                          \
      const int ko_ = (TN) << 6;                                               \
      const size_t kko_ = (size_t)(TN) * 8192;                                 \
      VFN[0][0] = *(const short8*)(vp0 + ko_);                                 \
      VFN[0][1] = *(const short8*)(vp1 + ko_);                                 \
      VFN[0][2] = *(const short8*)(vp2 + ko_);                                 \
      VFN[0][3] = *(const short8*)(vp3 + ko_);                                 \
      VFN[1][0] = *(const short8*)(vp0 + ko_ + 32);                            \
      VFN[1][1] = *(const short8*)(vp1 + ko_ + 32);                            \
      VFN[1][2] = *(const short8*)(vp2 + ko_ + 32);                            \
      VFN[1][3] = *(const short8*)(vp3 + ko_ + 32);                            \
      KN0 = *(const short8*)(Kp + kko_);                                       \
      KN1 = *(const short8*)(Kp + kko_ + 64);                                  \
    }                                                                          \
    _Pragma("unroll") for (int ks = 0; ks < 2; ++ks) {                         \
      short8 pf_[4];                                                           \
      _Pragma("unroll") for (int t16 = 0; t16 < 4; ++t16)                      \
        pf_[t16] = *(const short8*)(Pb_ + (16 * t16 + lc) * 128 +              \
                                    ((64 * ks + 16 * lg) ^ pkey));             \
      __builtin_amdgcn_s_setprio(1);                                           \
      _Pragma("unroll") for (int ct = 0; ct < 4; ++ct)                         \
        _Pragma("unroll") for (int t16 = 0; t16 < 4; ++t16)                    \
          acc16[t16][ct] = __builtin_amdgcn_mfma_f32_16x16x32_bf16(            \
              pf_[t16], VFC[ks][ct], acc16[t16][ct], 0, 0, 0);                 \
      __builtin_amdgcn_s_setprio(0);                                           \
    }                                                                          \
    asm volatile("" ::: "memory"); /* keep the prefetch inside this region */  \
  }

__global__ __launch_bounds__(256, 2) void flash_kernel(
    const unsigned short* __restrict__ Qt, const unsigned short* __restrict__ Kt,
    const unsigned short* __restrict__ V, const float* __restrict__ x,
    const float* __restrict__ gamma, float* __restrict__ out) {
  __shared__ unsigned short P[2][64 * 64];  // 2 x 8 KiB, swizzled
  __shared__ float den_lds[4][4][16];       // [wave][mt][lc]

  const int tid = threadIdx.x;
  const int lane = tid & 63;
  const int lc = lane & 15, lg = lane >> 4;
  const int w = tid >> 6;
  const int id = blockIdx.x;
  const int b = id & 7;                // batch == XCD (round-robin dispatch)
  const int m0 = (id >> 3) << 6;       // 64-row m-block

  // Q B-frags: qb[mt][ks] = Q[m0+16mt+lc][dk = 32ks+8lg .. +7]
  short8 qb[4][2];
#pragma unroll
  for (int mt = 0; mt < 4; ++mt)
#pragma unroll
    for (int ks = 0; ks < 2; ++ks)
      qb[mt][ks] = *(const short8*)(Qt + ((size_t)b * N_ + m0 + 16 * mt + lc) * 64 +
                                    32 * ks + 8 * lg);

  f32x4 acc16[4][4];  // [t16 m-subtile][ct c-subtile]
#pragma unroll
  for (int t16 = 0; t16 < 4; ++t16)
#pragma unroll
    for (int ct = 0; ct < 4; ++ct)
#pragma unroll
      for (int r = 0; r < 4; ++r) acc16[t16][ct][r] = 0.f;
  float den[4] = {0.f, 0.f, 0.f, 0.f};

  // K base: row kv = kv0 + 16w + lc, dk bytes 16lg + {0,64}; +8192B per iter
  const char* Kp = (const char*)Kt + ((size_t)b * N_ + 16 * w + lc) * 128 + 16 * lg;
  // V row pointers: c = 64w + 16ct + lc, kv elem 8lg
  const unsigned short* vp0 = V + ((size_t)b * C_ + 64 * w + 0  + lc) * N_ + 8 * lg;
  const unsigned short* vp1 = V + ((size_t)b * C_ + 64 * w + 16 + lc) * N_ + 8 * lg;
  const unsigned short* vp2 = V + ((size_t)b * C_ + 64 * w + 32 + lc) * N_ + 8 * lg;
  const unsigned short* vp3 = V + ((size_t)b * C_ + 64 * w + 48 + lc) * N_ + 8 * lg;

  const int pkey = (lc & 7) << 4;      // P swizzle key (m&7 == lc&7)
  const int pwcol = (32 * w + 8 * lg) ^ pkey;  // P-write column byte

  // ping-pong operand buffers
  short8 vfA[2][4], vfB[2][4];
  short8 kfA0, kfA1, kfB0, kfB1;

  // prologue: iteration-0 operands into A
  vfA[0][0] = *(const short8*)(vp0);      vfA[0][1] = *(const short8*)(vp1);
  vfA[0][2] = *(const short8*)(vp2);      vfA[0][3] = *(const short8*)(vp3);
  vfA[1][0] = *(const short8*)(vp0 + 32); vfA[1][1] = *(const short8*)(vp1 + 32);
  vfA[1][2] = *(const short8*)(vp2 + 32); vfA[1][3] = *(const short8*)(vp3 + 32);
  kfA0 = *(const short8*)(Kp);
  kfA1 = *(const short8*)(Kp + 64);

  for (int t = 0; t < 64; t += 2) {
    const int tn1 = t + 1;               // always <= 63
    ITER_BODY(vfA, kfA0, kfA1, vfB, kfB0, kfB1, 0, tn1);
    const int tn2 = (t + 2) & 63;        // wraps only on the final trip
    ITER_BODY(vfB, kfB0, kfB1, vfA, kfA0, kfA1, 1, tn2);
  }

  // ---- den reduction: lg-groups (shfl) then cross-wave (LDS) ----
#pragma unroll
  for (int mt = 0; mt < 4; ++mt) {
    float d = den[mt];
    d += __shfl_xor(d, 16);
    d += __shfl_xor(d, 32);
    if (lg == 0) den_lds[w][mt][lc] = d;
  }
  __syncthreads();

  const float g = gamma[0];
  float ig[4];
#pragma unroll
  for (int mt = 0; mt < 4; ++mt) {
    float dtot = den_lds[0][mt][lc] + den_lds[1][mt][lc] +
                 den_lds[2][mt][lc] + den_lds[3][mt][lc];
    ig[mt] = g / dtot;  // lane's lc: gamma/den for m-row m0+16mt+lc
  }

  // ---- epilogue: lane holds O[m=16t16+4lg+r][c=16ct+lc]; f32x4 over m ----
#pragma unroll
  for (int t16 = 0; t16 < 4; ++t16) {
    f32x4 idn;
#pragma unroll
    for (int r = 0; r < 4; ++r)
      idn[r] = __shfl(ig[t16], 4 * lg + r);
#pragma unroll
    for (int ct = 0; ct < 4; ++ct) {
      size_t off = ((size_t)b * C_ + 64 * w + 16 * ct + lc) * N_ + m0 + 16 * t16 + 4 * lg;
      f32x4 xv = *(const f32x4*)(x + off);
      f32x4 o;
#pragma unroll
      for (int r = 0; r < 4; ++r) o[r] = xv[r] + idn[r] * acc16[t16][ct][r];
      *(f32x4*)(out + off) = o;
    }
  }
}

// ---------------------------------------------------------------------------
extern "C" void kernel_launch(void* const* d_in, const int* in_sizes, int n_in,
                              void* d_out, int out_size, void* d_ws, size_t ws_size,
                              hipStream_t stream) {
  const float* x = (const float*)d_in[0];
  const float* Wq = (const float*)d_in[1];
  const float* bq = (const float*)d_in[2];
  const float* Wk = (const float*)d_in[3];
  const float* bk = (const float*)d_in[4];
  const float* Wv = (const float*)d_in[5];
  const float* bv = (const float*)d_in[6];
  const float* gamma = (const float*)d_in[7];
  float* out = (float*)d_out;

  char* ws = (char*)d_ws;
  unsigned short* Wc = (unsigned short*)(ws);                    // 196608 B
  float* biasc = (float*)(ws + 196608);                          // 1536 B
  unsigned short* Qt = (unsigned short*)(ws + 198144);           // 4 MiB
  unsigned short* Kt = (unsigned short*)(ws + 198144 + 4194304); // 4 MiB
  unsigned short* Vv = (unsigned short*)(ws + 198144 + 8388608); // 16 MiB
  // total ws use: ~25.4 MB

  prep_kernel<<<384, 256, 0, stream>>>(Wq, bq, Wk, bk, Wv, bv, Wc, biasc);
  proj_kernel<<<dim3(64, 8), 256, 0, stream>>>(x, Wc, biasc, Qt, Kt, Vv);
  flash_kernel<<<512, 256, 0, stream>>>(Qt, Kt, Vv, x, gamma, out);
}

// Round 13
// 136.447 us; speedup vs baseline: 2.3763x; 1.4463x over previous
//
#include <hip/hip_runtime.h>

// Self-attention block (non-local): B=8, C=256, H=W=64 -> N=4096, dk=64.
// out = x + gamma * softmax((Wq x)^T (Wk x) / 8) applied to (Wv x).
// prep (weights->bf16, fold log2e/8 into Wq) -> proj (MFMA GEMM) -> flash.
// R13 flash: kv-block 64, m-block 64, grid 512.  V staged to LDS via
// global_load_lds DMA (un-sinkable, un-spillable), DOUBLE-buffered: DMA for
// t+1 issues in region B(t) and is drained by BAR(t+1) one full iteration
// later (zero exposed transfer).  Balanced 16-slot XOR swizzle for both V
// and P (pair-interleaved 256B rows, key (row&15)<<4): 64 lanes -> 16 slots
// x 4 distinct addrs = ds_read_b128 floor.  K via ping-pong regs issued
// BEFORE the DMA so the kf wait is vmcnt(8).  ONE barrier per iteration.
// Max-free softmax (logits O(1) by construction), direct f32x4 epilogue.

typedef __attribute__((ext_vector_type(8)))  short short8;
typedef __attribute__((ext_vector_type(4)))  short short4v;
typedef __attribute__((ext_vector_type(16))) float f32x16;
typedef __attribute__((ext_vector_type(4)))  float f32x4;

#define B_   8
#define C_   256
#define N_   4096
#define DK_  64
// log2(e) / sqrt(dk) = 1.4426950408889634 / 8
#define QSCL 0.18033688011112043f

#if defined(__has_builtin)
#if __has_builtin(__builtin_amdgcn_exp2f)
#define EXP2F(x) __builtin_amdgcn_exp2f(x)
#else
#define EXP2F(x) exp2f(x)
#endif
#else
#define EXP2F(x) exp2f(x)
#endif

// float -> bf16 bits, round-to-nearest-even (inputs are finite; no NaN path)
__device__ __forceinline__ unsigned short bfb(float f) {
  unsigned u = __builtin_bit_cast(unsigned, f);
  unsigned r = (u + 0x7fffu + ((u >> 16) & 1u)) >> 16;
  return (unsigned short)r;
}

// packed f32x2 -> bf16x2 (low = a, high = b), RNE
__device__ __forceinline__ unsigned cvtpk(float a, float b) {
  unsigned r;
  asm("v_cvt_pk_bf16_f32 %0, %1, %2" : "=v"(r) : "v"(a), "v"(b));
  return r;
}

// ---------------------------------------------------------------------------
// Kernel 1: weight prep.  W'[384][256] bf16 = [Wq*QSCL ; Wk ; Wv], bias'[384].
// ---------------------------------------------------------------------------
__global__ void prep_kernel(const float* __restrict__ Wq, const float* __restrict__ bq,
                            const float* __restrict__ Wk, const float* __restrict__ bk,
                            const float* __restrict__ Wv, const float* __restrict__ bv,
                            unsigned short* __restrict__ Wc, float* __restrict__ biasc) {
  int idx = blockIdx.x * 256 + threadIdx.x;
  if (idx < 384 * 256) {
    int ch = idx >> 8, c = idx & 255;
    float v;
    if (ch < 64)       v = Wq[ch * 256 + c] * QSCL;
    else if (ch < 128) v = Wk[(ch - 64) * 256 + c];
    else               v = Wv[(ch - 128) * 256 + c];
    Wc[idx] = bfb(v);
  }
  if (idx < 384) {
    float bb;
    if (idx < 64)       bb = bq[idx] * QSCL;
    else if (idx < 128) bb = bk[idx - 64];
    else                bb = bv[idx - 128];
    biasc[idx] = bb;
  }
}

// ---------------------------------------------------------------------------
// Kernel 2: projections.  Per (batch, 64-row n-block): stage x[256c][64n]
// transposed into LDS as bf16 (XOR-swizzled), then OUT[n][ch] = Xt * W'^T via
// 32x32x16 bf16 MFMA.  Outputs: Qt,Kt [B][N][64] (n-major), V [B][C][N].
// ---------------------------------------------------------------------------
__global__ __launch_bounds__(256, 2) void proj_kernel(
    const float* __restrict__ x, const unsigned short* __restrict__ Wc,
    const float* __restrict__ biasc, unsigned short* __restrict__ Qt,
    unsigned short* __restrict__ Kt, unsigned short* __restrict__ V) {
  __shared__ unsigned short XT[64 * 256];  // [n][c] bf16, swizzled, 32 KiB
  const int tid = threadIdx.x;
  const int b = blockIdx.y;
  const int n0 = blockIdx.x * 64;

  // stage: x[b][c][n0+0..63] fp32 -> XT[n][c] bf16 (transpose), swizzle:
  // ushort idx = n*256 + (((c>>3) ^ (n&15))<<3) + (c&7)
  {
    const f32x4* x4 = (const f32x4*)(x + ((size_t)b * C_) * N_ + n0);
    int c = tid >> 4;                  // 0..15 (+16 per pass)
    const int nl = (tid & 15) << 2;    // 0,4,...,60
#pragma unroll
    for (int p = 0; p < 16; ++p, c += 16) {
      f32x4 v = x4[(size_t)c * (N_ / 4) + (nl >> 2)];
#pragma unroll
      for (int i = 0; i < 4; ++i) {
        int n = nl + i;
        XT[n * 256 + ((((c >> 3) ^ (n & 15)) << 3) | (c & 7))] = bfb(v[i]);
      }
    }
  }
  __syncthreads();

  const int lane = tid & 63, li = lane & 31, hi = lane >> 5;
  const int w = tid >> 6;
  const int ch0 = 96 * w;  // this wave's 96 output channels (3 x 32)

  f32x16 acc[2][3];
#pragma unroll
  for (int mt = 0; mt < 2; ++mt)
#pragma unroll
    for (int j = 0; j < 3; ++j)
#pragma unroll
      for (int r = 0; r < 16; ++r) acc[mt][j][r] = 0.f;

  const short8* Wc8 = (const short8*)Wc;
#pragma unroll
  for (int ks = 0; ks < 16; ++ks) {
    // A-frags: lane holds Xt[n=32*mt+li][c=16*ks+8*hi .. +8]
    int chunk = 2 * ks + hi;
    short8 a0 = *(const short8*)&XT[(li) * 256 + ((chunk ^ (li & 15)) << 3)];
    short8 a1 = *(const short8*)&XT[(32 + li) * 256 + ((chunk ^ (li & 15)) << 3)];
#pragma unroll
    for (int j = 0; j < 3; ++j) {
      short8 bf = Wc8[(size_t)(ch0 + 32 * j + li) * 32 + chunk];
      acc[0][j] = __builtin_amdgcn_mfma_f32_32x32x16_bf16(a0, bf, acc[0][j], 0, 0, 0);
      acc[1][j] = __builtin_amdgcn_mfma_f32_32x32x16_bf16(a1, bf, acc[1][j], 0, 0, 0);
    }
  }

  // epilogue: D[row=n][col=ch], row = (r&3)+8*(r>>2)+4*hi + 32*mt, col = li
#pragma unroll
  for (int j = 0; j < 3; ++j) {
    const int chb = ch0 + 32 * j;  // wave-uniform 32-block, never straddles Q/K/V
    const int ch = chb + li;
    const float bias = biasc[ch];
#pragma unroll
    for (int mt = 0; mt < 2; ++mt) {
      if (chb < 64) {
#pragma unroll
        for (int r = 0; r < 16; ++r) {
          int n = n0 + 32 * mt + (r & 3) + 8 * (r >> 2) + 4 * hi;
          Qt[((size_t)(b * N_ + n) << 6) + ch] = bfb(acc[mt][j][r] + bias);
        }
      } else if (chb < 128) {
#pragma unroll
        for (int r = 0; r < 16; ++r) {
          int n = n0 + 32 * mt + (r & 3) + 8 * (r >> 2) + 4 * hi;
          Kt[((size_t)(b * N_ + n) << 6) + (ch - 64)] = bfb(acc[mt][j][r] + bias);
        }
      } else {
        const int cv = ch - 128;
#pragma unroll
        for (int q = 0; q < 4; ++q) {  // 4 consecutive n per 8B store
          short4v pk;
#pragma unroll
          for (int i = 0; i < 4; ++i) pk[i] = (short)bfb(acc[mt][j][4 * q + i] + bias);
          int n = n0 + 32 * mt + 8 * q + 4 * hi;
          *(short4v*)&V[(size_t)(b * C_ + cv) * N_ + n] = pk;
        }
      }
    }
  }
}

// ---------------------------------------------------------------------------
// Kernel 3: attention.  Grid 512 x 256 threads (4 waves).
// b = id & 7 (batch <-> XCD), m0 = (id >> 3)*64.  kv-block 64, 64 iters.
// LDS byte layout (both V and P, pair-interleaved, balanced 16-slot swizzle):
//   stored(row, kv) = (row>>1)*256 + (((row&1)*128 + kv*2) ^ ((row&15)<<4))
// where row = c (V tile, 256 rows) or m_local (P tile, 64 rows).
// Iter t: A: S via 16x16x32 (K regs, wait~0) -> exp2 -> P[t&1]; BAR (drains
// DMA(V(t)) issued last iter + P writes); B: load K(t+1) regs, THEN issue
// DMA V(t+1)->Vbuf[(t+1)&1] (safe: BAR(t) retired all B(t-1) readers), then
// PV 16x16x32 from P[t&1] + Vbuf[t&1].
// ---------------------------------------------------------------------------
#define PVMFMA(PF0, PF1, PF2, PF3, VF0, VF1, VF2, VF3)                         \
  do {                                                                         \
    __builtin_amdgcn_s_setprio(1);                                             \
    acc16[0][0] = __builtin_amdgcn_mfma_f32_16x16x32_bf16(PF0, VF0, acc16[0][0], 0, 0, 0); \
    acc16[1][0] = __builtin_amdgcn_mfma_f32_16x16x32_bf16(PF1, VF0, acc16[1][0], 0, 0, 0); \
    acc16[2][0] = __builtin_amdgcn_mfma_f32_16x16x32_bf16(PF2, VF0, acc16[2][0], 0, 0, 0); \
    acc16[3][0] = __builtin_amdgcn_mfma_f32_16x16x32_bf16(PF3, VF0, acc16[3][0], 0, 0, 0); \
    acc16[0][1] = __builtin_amdgcn_mfma_f32_16x16x32_bf16(PF0, VF1, acc16[0][1], 0, 0, 0); \
    acc16[1][1] = __builtin_amdgcn_mfma_f32_16x16x32_bf16(PF1, VF1, acc16[1][1], 0, 0, 0); \
    acc16[2][1] = __builtin_amdgcn_mfma_f32_16x16x32_bf16(PF2, VF1, acc16[2][1], 0, 0, 0); \
    acc16[3][1] = __builtin_amdgcn_mfma_f32_16x16x32_bf16(PF3, VF1, acc16[3][1], 0, 0, 0); \
    acc16[0][2] = __builtin_amdgcn_mfma_f32_16x16x32_bf16(PF0, VF2, acc16[0][2], 0, 0, 0); \
    acc16[1][2] = __builtin_amdgcn_mfma_f32_16x16x32_bf16(PF1, VF2, acc16[1][2], 0, 0, 0); \
    acc16[2][2] = __builtin_amdgcn_mfma_f32_16x16x32_bf16(PF2, VF2, acc16[2][2], 0, 0, 0); \
    acc16[3][2] = __builtin_amdgcn_mfma_f32_16x16x32_bf16(PF3, VF2, acc16[3][2], 0, 0, 0); \
    acc16[0][3] = __builtin_amdgcn_mfma_f32_16x16x32_bf16(PF0, VF3, acc16[0][3], 0, 0, 0); \
    acc16[1][3] = __builtin_amdgcn_mfma_f32_16x16x32_bf16(PF1, VF3, acc16[1][3], 0, 0, 0); \
    acc16[2][3] = __builtin_amdgcn_mfma_f32_16x16x32_bf16(PF2, VF3, acc16[2][3], 0, 0, 0); \
    acc16[3][3] = __builtin_amdgcn_mfma_f32_16x16x32_bf16(PF3, VF3, acc16[3][3], 0, 0, 0); \
    __builtin_amdgcn_s_setprio(0);                                             \
  } while (0)

#define FITER(KC0, KC1, KN0, KN1, PB, VB, VN, TN)                              \
  {                                                                            \
    _Pragma("unroll") for (int mt = 0; mt < 4; ++mt) {                         \
      f32x4 st = {0.f, 0.f, 0.f, 0.f};                                         \
      st = __builtin_amdgcn_mfma_f32_16x16x32_bf16(KC0, qb[mt][0], st, 0, 0, 0); \
      st = __builtin_amdgcn_mfma_f32_16x16x32_bf16(KC1, qb[mt][1], st, 0, 0, 0); \
      float e0 = EXP2F(st[0]), e1 = EXP2F(st[1]);                              \
      float e2 = EXP2F(st[2]), e3 = EXP2F(st[3]);                              \
      den[mt] += (e0 + e1) + (e2 + e3);                                        \
      unsigned lo_ = cvtpk(e0, e1), hh_ = cvtpk(e2, e3);                       \
      unsigned long long vv_ =                                                 \
          (unsigned long long)lo_ | ((unsigned long long)hh_ << 32);           \
      *(unsigned long long*)((PB) + 2048 * mt + prow_base + pwoff) = vv_;      \
    }                                                                          \
    __syncthreads(); /* drains DMA(V(t)) + P writes */                         \
    KN0 = *(const short8*)(Kp + (size_t)(TN) * 8192);                          \
    KN1 = *(const short8*)(Kp + (size_t)(TN) * 8192 + 64);                     \
    asm volatile("" ::: "memory"); /* K loads stay ABOVE the DMA issues */     \
    _Pragma("unroll") for (int j = 0; j < 8; ++j)                              \
      __builtin_amdgcn_global_load_lds(                                        \
          (const __attribute__((address_space(1))) unsigned int*)(srcp[j] +    \
                                                                  (size_t)(TN) * 128), \
          (__attribute__((address_space(3))) unsigned int*)((VN) + w * 8192 +  \
                                                            j * 1024),         \
          16, 0, 0);                                                           \
    {                                                                          \
      const char* vwb_ = (VB) + w * 8192 + prow_base;                          \
      const char* pb_ = (PB) + prow_base;                                      \
      short8 pf0 = *(const short8*)(pb_ + off2_0);                             \
      short8 pf1 = *(const short8*)(pb_ + 2048 + off2_0);                      \
      short8 pf2 = *(const short8*)(pb_ + 4096 + off2_0);                      \
      short8 pf3 = *(const short8*)(pb_ + 6144 + off2_0);                      \
      short8 vf0 = *(const short8*)(vwb_ + off2_0);                            \
      short8 vf1 = *(const short8*)(vwb_ + 2048 + off2_0);                     \
      short8 vf2 = *(const short8*)(vwb_ + 4096 + off2_0);                     \
      short8 vf3 = *(const short8*)(vwb_ + 6144 + off2_0);                     \
      PVMFMA(pf0, pf1, pf2, pf3, vf0, vf1, vf2, vf3);                          \
      pf0 = *(const short8*)(pb_ + off2_1);                                    \
      pf1 = *(const short8*)(pb_ + 2048 + off2_1);                             \
      pf2 = *(const short8*)(pb_ + 4096 + off2_1);                             \
      pf3 = *(const short8*)(pb_ + 6144 + off2_1);                             \
      vf0 = *(const short8*)(vwb_ + off2_1);                                   \
      vf1 = *(const short8*)(vwb_ + 2048 + off2_1);                            \
      vf2 = *(const short8*)(vwb_ + 4096 + off2_1);                            \
      vf3 = *(const short8*)(vwb_ + 6144 + off2_1);                            \
      PVMFMA(pf0, pf1, pf2, pf3, vf0, vf1, vf2, vf3);                          \
    }                                                                          \
  }

__global__ __launch_bounds__(256, 2) void flash_kernel(
    const unsigned short* __restrict__ Qt, const unsigned short* __restrict__ Kt,
    const unsigned short* __restrict__ V, const float* __restrict__ x,
    const float* __restrict__ gamma, float* __restrict__ out) {
  __shared__ char SMEM[81920];
  char* VT0 = SMEM;                 // 32 KiB V buffer (even t)
  char* VT1 = SMEM + 32768;         // 32 KiB V buffer (odd t)
  char* PT0 = SMEM + 65536;         // 8 KiB P buffer (even t)
  char* PT1 = SMEM + 73728;         // 8 KiB P buffer (odd t)

  const int tid = threadIdx.x;
  const int lane = tid & 63;
  const int lc = lane & 15, lg = lane >> 4;
  const int w = tid >> 6;
  const int id = blockIdx.x;
  const int b = id & 7;                // batch == XCD (round-robin dispatch)
  const int m0 = (id >> 3) << 6;       // 64-row m-block

  // Q B-frags: qb[mt][ks] = Q[m0+16mt+lc][dk = 32ks+8lg .. +7]
  short8 qb[4][2];
#pragma unroll
  for (int mt = 0; mt < 4; ++mt)
#pragma unroll
    for (int ks = 0; ks < 2; ++ks)
      qb[mt][ks] = *(const short8*)(Qt + ((size_t)b * N_ + m0 + 16 * mt + lc) * 64 +
                                    32 * ks + 8 * lg);

  f32x4 acc16[4][4];  // [t16 m-subtile][ct c-subtile]
#pragma unroll
  for (int t16 = 0; t16 < 4; ++t16)
#pragma unroll
    for (int ct = 0; ct < 4; ++ct)
#pragma unroll
      for (int r = 0; r < 4; ++r) acc16[t16][ct][r] = 0.f;
  float den[4] = {0.f, 0.f, 0.f, 0.f};

  // K base: row kv = 64t + 16w + lc, dk bytes 16lg + {0,64}
  const char* Kp = (const char*)Kt + ((size_t)b * N_ + 16 * w + lc) * 128 + 16 * lg;

  // DMA source decode: LDS chunk at L = w*8192 + j*1024 + lane*16 holds
  // V[c][kv0+kvb/2 ..] where rp=L>>8, off=L&255, h=(off>>7)^((rp>>2)&1),
  // c=2rp+h, kvb=(off^((c&15)<<4))&127.  (Verified round-trip vs read map.)
  const char* vsb = (const char*)V + (size_t)b * C_ * (N_ * 2);
  const char* srcp[8];
#pragma unroll
  for (int j = 0; j < 8; ++j) {
    int L = w * 8192 + j * 1024 + lane * 16;
    int rp = L >> 8, off = L & 255;
    int h = ((off >> 7) ^ (rp >> 2)) & 1;
    int c = 2 * rp + h;
    int kvb = (off ^ ((c & 15) << 4)) & 127;  // byte offset = kv*2
    srcp[j] = vsb + (size_t)c * (N_ * 2) + kvb;
  }

  // swizzle constants (shared by P and V maps; key = (row&15)<<4 = lc<<4)
  const int pkey = lc << 4;
  const int off2_0 = ((((lc & 1) << 7) | (16 * lg))) ^ pkey;       // read, ks=0
  const int off2_1 = ((((lc & 1) << 7) | 64 | (16 * lg))) ^ pkey;  // read, ks=1
  const int pwoff = ((((lc & 1) << 7) | (32 * w) | (8 * lg))) ^ pkey;  // P write
  const int prow_base = (lc >> 1) * 256;

  // prologue: K(0) regs, then DMA V(0) -> VT0
  short8 kfA0, kfA1, kfB0, kfB1;
  kfA0 = *(const short8*)(Kp);
  kfA1 = *(const short8*)(Kp + 64);
  asm volatile("" ::: "memory");
#pragma unroll
  for (int j = 0; j < 8; ++j)
    __builtin_amdgcn_global_load_lds(
        (const __attribute__((address_space(1))) unsigned int*)(srcp[j]),
        (__attribute__((address_space(3))) unsigned int*)(VT0 + w * 8192 + j * 1024),
        16, 0, 0);

  for (int t = 0; t < 64; t += 2) {
    const int tn1 = t + 1;               // <= 63
    FITER(kfA0, kfA1, kfB0, kfB1, PT0, VT0, VT1, tn1);
    const int tn2 = (t + 2) & 63;        // wraps only on the last trip (harmless)
    FITER(kfB0, kfB1, kfA0, kfA1, PT1, VT1, VT0, tn2);
  }

  // ---- den reduction: lg-groups (shfl) then cross-wave via LDS (alias PT0;
  //      last PT0 read was B(62), separated by BAR(63)) ----
  float* den_lds = (float*)PT0;  // [w][mt][lc] = w*64 + mt*16 + lc
#pragma unroll
  for (int mt = 0; mt < 4; ++mt) {
    float d = den[mt];
    d += __shfl_xor(d, 16);
    d += __shfl_xor(d, 32);
    if (lg == 0) den_lds[w * 64 + mt * 16 + lc] = d;
  }
  __syncthreads();

  const float g = gamma[0];
  float ig[4];
#pragma unroll
  for (int mt = 0; mt < 4; ++mt) {
    float dtot = den_lds[0 * 64 + mt * 16 + lc] + den_lds[1 * 64 + mt * 16 + lc] +
                 den_lds[2 * 64 + mt * 16 + lc] + den_lds[3 * 64 + mt * 16 + lc];
    ig[mt] = g / dtot;  // lane's lc: gamma/den for m-row m0+16mt+lc
  }

  // ---- epilogue: lane holds O[m=16t16+4lg+r][c=16ct+lc]; f32x4 over m ----
#pragma unroll
  for (int t16 = 0; t16 < 4; ++t16) {
    f32x4 idn;
#pragma unroll
    for (int r = 0; r < 4; ++r)
      idn[r] = __shfl(ig[t16], 4 * lg + r);
#pragma unroll
    for (int ct = 0; ct < 4; ++ct) {
      size_t off = ((size_t)b * C_ + 64 * w + 16 * ct + lc) * N_ + m0 + 16 * t16 + 4 * lg;
      f32x4 xv = *(const f32x4*)(x + off);
      f32x4 o;
#pragma unroll
      for (int r = 0; r < 4; ++r) o[r] = xv[r] + idn[r] * acc16[t16][ct][r];
      *(f32x4*)(out + off) = o;
    }
  }
}

// ---------------------------------------------------------------------------
extern "C" void kernel_launch(void* const* d_in, const int* in_sizes, int n_in,
                              void* d_out, int out_size, void* d_ws, size_t ws_size,
                              hipStream_t stream) {
  const float* x = (const float*)d_in[0];
  const float* Wq = (const float*)d_in[1];
  const float* bq = (const float*)d_in[2];
  const float* Wk = (const float*)d_in[3];
  const float* bk = (const float*)d_in[4];
  const float* Wv = (const float*)d_in[5];
  const float* bv = (const float*)d_in[6];
  const float* gamma = (const float*)d_in[7];
  float* out = (float*)d_out;

  char* ws = (char*)d_ws;
  unsigned short* Wc = (unsigned short*)(ws);                    // 196608 B
  float* biasc = (float*)(ws + 196608);                          // 1536 B
  unsigned short* Qt = (unsigned short*)(ws + 198144);           // 4 MiB
  unsigned short* Kt = (unsigned short*)(ws + 198144 + 4194304); // 4 MiB
  unsigned short* Vv = (unsigned short*)(ws + 198144 + 8388608); // 16 MiB
  // total ws use: ~25.4 MB

  prep_kernel<<<384, 256, 0, stream>>>(Wq, bq, Wk, bk, Wv, bv, Wc, biasc);
  proj_kernel<<<dim3(64, 8), 256, 0, stream>>>(x, Wc, biasc, Qt, Kt, Vv);
  flash_kernel<<<512, 256, 0, stream>>>(Qt, Kt, Vv, x, gamma, out);
}